// Round 7
// baseline (244.476 us; speedup 1.0000x reference)
//
#include <hip/hip_runtime.h>

// Problem constants
#define Bb 2
#define Qq 2048
#define Ss 2048
#define Dd 1024
#define Hh 16
#define AD 64
#define KK 1024

typedef __attribute__((ext_vector_type(8))) short bf16x8;
typedef __attribute__((ext_vector_type(4))) short bf16x4;
typedef __attribute__((ext_vector_type(4))) float f32x4;
typedef unsigned short u16;
typedef unsigned int u32;
typedef unsigned long long u64;

__device__ __forceinline__ u16 f2bf(float f) {
  union { float f; u32 u; } v; v.f = f;
  u32 r = v.u + 0x7fffu + ((v.u >> 16) & 1u);  // RNE
  return (u16)(r >> 16);
}

// async 16B global->LDS DMA (dest = wave-uniform base + lane*16)
__device__ __forceinline__ void gld16(const u16* g, u16* l) {
  __builtin_amdgcn_global_load_lds(
      (const __attribute__((address_space(1))) unsigned int*)g,
      (__attribute__((address_space(3))) unsigned int*)l, 16, 0, 0);
}

// ------------- fused f32->bf16 cast (5 inputs) + mask bit-pack -------------
__global__ __launch_bounds__(256) void cast_all_k(const float* __restrict__ iQ,
                                                  const float* __restrict__ iK,
                                                  const float* __restrict__ Wq,
                                                  const float* __restrict__ Wkv,
                                                  const float* __restrict__ Wo,
                                                  const int* __restrict__ mask,
                                                  u16* __restrict__ Qb, u16* __restrict__ Kb,
                                                  u16* __restrict__ Wqb, u16* __restrict__ Wkvb,
                                                  u16* __restrict__ Wob,
                                                  u64* __restrict__ mb64) {
  int i = blockIdx.x * 256 + threadIdx.x;   // float4 index, casts cover [0, 3145728)
  if (i < 3145728) {
    const float* src; u16* dst; int off;
    if (i < 1048576)      { src = iQ;  dst = Qb;   off = 0; }
    else if (i < 2097152) { src = iK;  dst = Kb;   off = 1048576; }
    else if (i < 2359296) { src = Wq;  dst = Wqb;  off = 2097152; }
    else if (i < 2883584) { src = Wkv; dst = Wkvb; off = 2359296; }
    else                  { src = Wo;  dst = Wob;  off = 2883584; }
    int j = i - off;
    float4 v = ((const float4*)src)[j];
    ushort4 o;
    o.x = f2bf(v.x); o.y = f2bf(v.y); o.z = f2bf(v.z); o.w = f2bf(v.w);
    ((ushort4*)dst)[j] = o;
  } else {
    int flat = i - 3145728;                 // [0, 131072)
    int st = flat & 31;
    int q  = (flat >> 5) & 2047;
    int b  = flat >> 16;
    const int4* src = (const int4*)(mask + ((size_t)(b * Qq + q)) * Ss + st * 64);
    u64 bits = 0;
#pragma unroll
    for (int c = 0; c < 16; c++) {
      int4 v = src[c];
      bits |= (u64)(v.x != 0) << (c * 4 + 0);
      bits |= (u64)(v.y != 0) << (c * 4 + 1);
      bits |= (u64)(v.z != 0) << (c * 4 + 2);
      bits |= (u64)(v.w != 0) << (c * 4 + 3);
    }
    mb64[flat] = bits;
  }
}

// ------------- fused projection GEMM: 128x128 tile, BK=64 (AI=64 FLOP/B) -------
// bid<256: RQ = (Qb@Wq^T)*0.125. bid in [256,768): KV-proj -- n0<1024: K-half ->
// compact Kc[4096][1024]; else V-half -> VT[b][h][d][s] via per-head LDS transpose.
// LDS rows 64 u16 = 8 x 16B chunks, chunk c stored at c^(row&7) (conflict-free).
__global__ __launch_bounds__(256, 3) void proj_k(const u16* __restrict__ Qb,
                                                 const u16* __restrict__ Kb,
                                                 const u16* __restrict__ Wqb,
                                                 const u16* __restrict__ Wkvb,
                                                 u16* __restrict__ RQ,
                                                 u16* __restrict__ Kc,
                                                 u16* __restrict__ VT) {
  __shared__ char LB[34816];                 // max(As+Ws = 32 KB, 2x Tt = 34 KB)
  u16* As = (u16*)LB;                        // [128][64]
  u16* Ws = (u16*)(LB + 16384);              // [128][64]
  const int tid = threadIdx.x;
  const int lane = tid & 63, wave = tid >> 6;
  const int qr = lane & 15, quad = lane >> 4;
  const int qs = qr & 7;
  const int bid = blockIdx.x;
  const bool isQ = bid < 256;
  const int b2 = isQ ? bid : bid - 256;
  const int m0 = (b2 & 31) * 128;            // m-fast: same-XCD blocks share A tiles
  const int n0 = (b2 >> 5) * 128;
  const u16* A = isQ ? Qb : Kb;
  const u16* W = isQ ? Wqb : Wkvb;
  const int wm = (wave >> 1) * 64, wn = (wave & 1) * 64;

  // staging: 4 issues A + 4 issues W, 32 rows x 8 chunks each
  const int sr = tid >> 3, sc = tid & 7;
  const u16 *aP[4], *wP[4];
  u16 *aL[4], *wL[4];
#pragma unroll
  for (int is = 0; is < 4; is++) {
    int row = is * 32 + sr;
    int goff = (sc ^ (row & 7)) * 8;
    aP[is] = A + (size_t)(m0 + row) * KK + goff;
    wP[is] = W + (size_t)(n0 + row) * KK + goff;
    aL[is] = As + row * 64 + sc * 8;
    wL[is] = Ws + row * 64 + sc * 8;
  }

  f32x4 acc[4][4] = {};

  for (int k0 = 0; k0 < KK; k0 += 64) {
#pragma unroll
    for (int is = 0; is < 4; is++) gld16(aP[is] + k0, aL[is]);
#pragma unroll
    for (int is = 0; is < 4; is++) gld16(wP[is] + k0, wL[is]);
    __syncthreads();
#pragma unroll
    for (int kk = 0; kk < 2; kk++) {
      bf16x8 af[4], bw[4];
      int ch = ((kk * 4 + quad) ^ qs) * 8;
#pragma unroll
      for (int i = 0; i < 4; i++)
        af[i] = *(const bf16x8*)(As + (wm + i * 16 + qr) * 64 + ch);
#pragma unroll
      for (int j = 0; j < 4; j++)
        bw[j] = *(const bf16x8*)(Ws + (wn + j * 16 + qr) * 64 + ch);
#pragma unroll
      for (int i = 0; i < 4; i++)
#pragma unroll
        for (int j = 0; j < 4; j++)
          acc[i][j] = __builtin_amdgcn_mfma_f32_16x16x32_bf16(af[i], bw[j], acc[i][j], 0, 0, 0);
    }
    __syncthreads();
  }

  if (isQ) {
#pragma unroll
    for (int i = 0; i < 4; i++)
#pragma unroll
      for (int j = 0; j < 4; j++)
#pragma unroll
        for (int r = 0; r < 4; r++) {
          int row = m0 + wm + i * 16 + quad * 4 + r;
          int col = n0 + wn + j * 16 + qr;
          RQ[(size_t)row * 1024 + col] = f2bf(acc[i][j][r] * 0.125f);  // fold QK scale
        }
  } else if (n0 < 1024) {
    // K-half -> compact Kc (stride 1024)
#pragma unroll
    for (int i = 0; i < 4; i++)
#pragma unroll
      for (int j = 0; j < 4; j++)
#pragma unroll
        for (int r = 0; r < 4; r++) {
          int row = m0 + wm + i * 16 + quad * 4 + r;
          int col = n0 + wn + j * 16 + qr;
          Kc[(size_t)row * 1024 + col] = f2bf(acc[i][j][r]);
        }
  } else {
    // V-half (covers 2 heads: wn selects head) -> per-head Tt[64 d][136 s] -> VT
    u16* Ttp = (u16*)LB + (wn >> 6) * (64 * 136);
#pragma unroll
    for (int i = 0; i < 4; i++)
#pragma unroll
      for (int j = 0; j < 4; j++)
#pragma unroll
        for (int r = 0; r < 4; r++) {
          int srow = wm + i * 16 + quad * 4 + r;   // local s in [0,128)
          int d    = j * 16 + qr;                  // local d in [0,64)
          Ttp[d * 136 + srow] = f2bf(acc[i][j][r]);
        }
    __syncthreads();
    const int h0 = (n0 - 1024) >> 6;               // first of the 2 heads
    const int bb = m0 >> 11, sbase = m0 & 2047;
    const u16* LB16 = (const u16*)LB;
    // 2 heads x 64 d x 128 s = 2048 int4 chunks: flat = hd(1)|d(6)|ch(4)
#pragma unroll
    for (int ic = 0; ic < 8; ic++) {
      int flat = ic * 256 + tid;                   // [0,2048)
      int hd = flat >> 10, d = (flat >> 4) & 63, ch = flat & 15;
      *(int4*)(VT + (((size_t)(bb * Hh + h0 + hd)) * AD + d) * Ss + sbase + ch * 8) =
          *(const int4*)(LB16 + hd * (64 * 136) + d * 136 + ch * 8);
    }
  }
}

// ------------- O-projection: d_out = Obuf @ Wo^T (f32), 128x128 BK=64 -------
__global__ __launch_bounds__(256, 3) void oproj_k(const u16* __restrict__ A,
                                                  const u16* __restrict__ W,
                                                  float* __restrict__ C) {
  __shared__ u16 As[128 * 64];
  __shared__ u16 Ws[128 * 64];
  const int tid = threadIdx.x;
  const int lane = tid & 63, wave = tid >> 6;
  const int qr = lane & 15, quad = lane >> 4;
  const int qs = qr & 7;
  const int m0 = (blockIdx.x & 31) * 128;
  const int n0 = (blockIdx.x >> 5) * 128;
  const int wm = (wave >> 1) * 64, wn = (wave & 1) * 64;
  const int sr = tid >> 3, sc = tid & 7;
  const u16 *aP[4], *wP[4];
  u16 *aL[4], *wL[4];
#pragma unroll
  for (int is = 0; is < 4; is++) {
    int row = is * 32 + sr;
    int goff = (sc ^ (row & 7)) * 8;
    aP[is] = A + (size_t)(m0 + row) * KK + goff;
    wP[is] = W + (size_t)(n0 + row) * KK + goff;
    aL[is] = As + row * 64 + sc * 8;
    wL[is] = Ws + row * 64 + sc * 8;
  }
  f32x4 acc[4][4] = {};
  for (int k0 = 0; k0 < KK; k0 += 64) {
#pragma unroll
    for (int is = 0; is < 4; is++) gld16(aP[is] + k0, aL[is]);
#pragma unroll
    for (int is = 0; is < 4; is++) gld16(wP[is] + k0, wL[is]);
    __syncthreads();
#pragma unroll
    for (int kk = 0; kk < 2; kk++) {
      bf16x8 af[4], bw[4];
      int ch = ((kk * 4 + quad) ^ qs) * 8;
#pragma unroll
      for (int i = 0; i < 4; i++)
        af[i] = *(const bf16x8*)(As + (wm + i * 16 + qr) * 64 + ch);
#pragma unroll
      for (int j = 0; j < 4; j++)
        bw[j] = *(const bf16x8*)(Ws + (wn + j * 16 + qr) * 64 + ch);
#pragma unroll
      for (int i = 0; i < 4; i++)
#pragma unroll
        for (int j = 0; j < 4; j++)
          acc[i][j] = __builtin_amdgcn_mfma_f32_16x16x32_bf16(af[i], bw[j], acc[i][j], 0, 0, 0);
    }
    __syncthreads();
  }
#pragma unroll
  for (int i = 0; i < 4; i++)
#pragma unroll
    for (int j = 0; j < 4; j++)
#pragma unroll
      for (int r = 0; r < 4; r++) {
        int row = m0 + wm + i * 16 + quad * 4 + r;
        int col = n0 + wn + j * 16 + qr;
        C[(size_t)row * 1024 + col] = acc[i][j][r];
      }
}

// ---------------- fused attention v5 (compact-K addressing) ----------------
__global__ __launch_bounds__(512, 4) void attn_k(const u16* __restrict__ RQ,
                                                 const u16* __restrict__ Kc,
                                                 const u16* __restrict__ VT,
                                                 const u64* __restrict__ mb64,
                                                 const float* __restrict__ nbias,
                                                 u16* __restrict__ O) {
  __shared__ char LB[65536];
  u16* Ks  = (u16*)LB;             // [256 s][64 d] 32 KB, chunk^(s&7)
  u16* Vts = (u16*)(LB + 32768);   // [64 d][256 s] 32 KB, chunk^(d&7)
  f32x4* Xch = (f32x4*)LB;         // epilogue exchange (40 KB), aliases

  const int tid = threadIdx.x, lane = tid & 63, w = tid >> 6;
  const int qh = w >> 1, sh = w & 1;
  const int qr = lane & 15, quad = lane >> 4;
  const int quad4 = quad * 4, qs = qr & 7;
  const int q0 = blockIdx.x * 128, h = blockIdx.y, b = blockIdx.z;
  const u16* rqb = RQ + ((size_t)(b * Qq + q0)) * Dd + h * AD;
  const u16* kb  = Kc + ((size_t)b * Ss) * 1024 + h * AD;
  const u16* vtb = VT + ((size_t)(b * Hh + h)) * AD * Ss;
  const u64* mbase = mb64 + ((size_t)(b * Qq + q0)) * 32;
  const float nb = nbias[0];

  // persistent Q fragments (B operand: n=q, k=d)
  bf16x8 bq[2][2];
#pragma unroll
  for (int j = 0; j < 2; j++)
#pragma unroll
    for (int kk = 0; kk < 2; kk++)
      bq[j][kk] = *(const bf16x8*)(rqb + (size_t)(qh * 32 + j * 16 + qr) * Dd +
                                   kk * 32 + quad * 8);

  // staging pointers
  const u16 *kP[4], *vP[4];
  u16 *kL[4], *vL[4];
  {
    const int r8 = tid >> 3, c8 = tid & 7;
#pragma unroll
    for (int is = 0; is < 4; is++) {
      int row = is * 64 + r8;
      kP[is] = kb + (size_t)row * 1024 + ((c8 ^ (row & 7)) * 8);
      kL[is] = Ks + row * 64 + c8 * 8;
    }
    const int r32 = tid >> 5, c32 = tid & 31;
#pragma unroll
    for (int is = 0; is < 4; is++) {
      int row = is * 16 + r32;
      vP[is] = vtb + (size_t)row * Ss + ((c32 ^ (row & 7)) * 8);
      vL[is] = Vts + row * 256 + c32 * 8;
    }
  }

  const bf16x4 vones = { (short)0x3F80, (short)0x3F80, (short)0x3F80, (short)0x3F80 };
  f32x4 acc[2][4] = {};
  f32x4 accd[2] = {};

  const u16* kfr = Ks + (sh * 128 + qr) * 64;
  const u16* kfr0 = kfr + ((quad ^ qs) * 8);
  const u16* kfr1 = kfr + (((quad + 4) ^ qs) * 8);

  for (int t = 0; t < 8; t++) {
    __syncthreads();
#pragma unroll
    for (int is = 0; is < 4; is++) gld16(kP[is] + (size_t)t * 262144, kL[is]);
#pragma unroll
    for (int is = 0; is < 4; is++) gld16(vP[is] + t * 256, vL[is]);
    u64 mw[2][2];
#pragma unroll
    for (int j = 0; j < 2; j++) {
      const u64* mp = mbase + (size_t)(qh * 32 + j * 16 + qr) * 32 + t * 4 + sh * 2;
      mw[j][0] = mp[0];
      mw[j][1] = mp[1];
    }
    __syncthreads();

#pragma unroll
    for (int mi = 0; mi < 8; mi++) {
      bf16x8 ak0 = *(const bf16x8*)(kfr0 + mi * 1024);
      bf16x8 ak1 = *(const bf16x8*)(kfr1 + mi * 1024);
      f32x4 asc0 = { nb, nb, nb, nb };
      f32x4 asc1 = { nb, nb, nb, nb };
      asc0 = __builtin_amdgcn_mfma_f32_16x16x32_bf16(ak0, bq[0][0], asc0, 0, 0, 0);
      asc0 = __builtin_amdgcn_mfma_f32_16x16x32_bf16(ak1, bq[0][1], asc0, 0, 0, 0);
      asc1 = __builtin_amdgcn_mfma_f32_16x16x32_bf16(ak0, bq[1][0], asc1, 0, 0, 0);
      asc1 = __builtin_amdgcn_mfma_f32_16x16x32_bf16(ak1, bq[1][1], asc1, 0, 0, 0);

      union { u32 w2[2]; bf16x4 v; } pk[2];
#pragma unroll
      for (int j = 0; j < 2; j++) {
        f32x4 asc = j ? asc1 : asc0;
        u32 mm = (u32)(mw[j][mi >> 2] >> ((mi & 3) * 16 + quad4)) & 0xFu;
        u32 th[4];
#pragma unroll
        for (int r = 0; r < 4; r++) {
          float tt = fmaxf(asc[r], 0.f);
          tt = tt * tt;
          if ((mm >> r) & 1) tt = 0.f;
          union { float f; u32 u; } cv; cv.f = tt;
          th[r] = cv.u;
        }
        pk[j].w2[0] = __builtin_amdgcn_perm(th[1], th[0], 0x07060302u);
        pk[j].w2[1] = __builtin_amdgcn_perm(th[3], th[2], 0x07060302u);
        accd[j] = __builtin_amdgcn_mfma_f32_16x16x16bf16_1k(pk[j].v, vones, accd[j], 0, 0, 0);
      }
      int g = ((sh * 32 + mi * 4 + quad) ^ (qs << 1)) * 4;
#pragma unroll
      for (int nn = 0; nn < 4; nn++) {
        bf16x4 bv = *(const bf16x4*)(Vts + (nn * 16 + qr) * 256 + g);
        acc[0][nn] = __builtin_amdgcn_mfma_f32_16x16x16bf16_1k(pk[0].v, bv, acc[0][nn], 0, 0, 0);
        acc[1][nn] = __builtin_amdgcn_mfma_f32_16x16x16bf16_1k(pk[1].v, bv, acc[1][nn], 0, 0, 0);
      }
    }
  }

  __syncthreads();
  if (sh == 1) {
#pragma unroll
    for (int j = 0; j < 2; j++) {
#pragma unroll
      for (int nn = 0; nn < 4; nn++)
        Xch[qh * 640 + (j * 4 + nn) * 64 + lane] = acc[j][nn];
      Xch[qh * 640 + (8 + j) * 64 + lane] = accd[j];
    }
  }
  __syncthreads();
  if (sh == 0) {
    u16* ob = O + ((size_t)(b * Qq + q0)) * Dd + h * AD;
#pragma unroll
    for (int j = 0; j < 2; j++) {
      f32x4 dpart = Xch[qh * 640 + (8 + j) * 64 + lane];
      float rc[4];
#pragma unroll
      for (int r = 0; r < 4; r++)
        rc[r] = 1.f / (accd[j][r] + dpart[r] + 1e-32f);
#pragma unroll
      for (int nn = 0; nn < 4; nn++) {
        f32x4 p4 = Xch[qh * 640 + (j * 4 + nn) * 64 + lane];
#pragma unroll
        for (int r = 0; r < 4; r++) {
          int ql = qh * 32 + j * 16 + quad * 4 + r;
          ob[(size_t)ql * Dd + nn * 16 + qr] = f2bf((acc[j][nn][r] + p4[r]) * rc[r]);
        }
      }
    }
  }
}

// ---------------- launch ----------------
extern "C" void kernel_launch(void* const* d_in, const int* in_sizes, int n_in,
                              void* d_out, int out_size, void* d_ws, size_t ws_size,
                              hipStream_t stream) {
  const float* iQ   = (const float*)d_in[0];
  const float* iK   = (const float*)d_in[1];
  const int*   mask = (const int*)d_in[2];
  const float* Wq   = (const float*)d_in[3];
  const float* Wkv  = (const float*)d_in[4];
  const float* Wo   = (const float*)d_in[5];
  const float* nb   = (const float*)d_in[6];

  char* ws = (char*)d_ws;
  u16* Qb   = (u16*)(ws + (size_t)0);          // 8 MB
  u16* Kb   = (u16*)(ws + ((size_t)8  << 20)); // 8 MB
  u16* Wqb  = (u16*)(ws + ((size_t)16 << 20)); // 2 MB
  u16* Wkvb = (u16*)(ws + ((size_t)18 << 20)); // 4 MB
  u16* Wob  = (u16*)(ws + ((size_t)22 << 20)); // 2 MB
  u16* RQ   = (u16*)(ws + ((size_t)24 << 20)); // 8 MB  (pre-scaled by 0.125)
  u16* Kc   = (u16*)(ws + ((size_t)32 << 20)); // 8 MB  (compact K, stride 1024)
  u16* Obuf = (u16*)(ws + ((size_t)48 << 20)); // 8 MB
  u16* VT   = (u16*)(ws + ((size_t)56 << 20)); // 8 MB
  u64* MB   = (u64*)(ws + ((size_t)64 << 20)); // 1 MB  -- total 65 MB

  cast_all_k<<<12800, 256, 0, stream>>>(iQ, iK, Wq, Wkv, Wo, mask,
                                        Qb, Kb, Wqb, Wkvb, Wob, MB);

  proj_k<<<768, 256, 0, stream>>>(Qb, Kb, Wqb, Wkvb, RQ, Kc, VT);

  attn_k<<<dim3(16, 16, 2), 512, 0, stream>>>(RQ, Kc, VT, MB, nb, Obuf);

  oproj_k<<<256, 256, 0, stream>>>(Obuf, Wob, (float*)d_out);
}